// Round 2
// baseline (479.173 us; speedup 1.0000x reference)
//
#include <hip/hip_runtime.h>

// ChannelAttention (XCA): B=4, N=8192, C=512, heads=4, dh=128.
// Inputs/outputs are FP32 (per reference dtypes). Intermediates bf16 in ws.
// Pipeline: QKV GEMM -> norms -> S=q.kT GEMM -> softmax -> xca GEMM -> out GEMM.
// Every GEMM is C[M][N] = A[M][K] * Bt[N][K]^T with K contiguous on both sides.

typedef unsigned short ushort_t;
typedef __attribute__((ext_vector_type(8))) short short8;
typedef __attribute__((ext_vector_type(4))) float float4v;
typedef __attribute__((ext_vector_type(4))) unsigned short ushort4v;

__device__ __forceinline__ float bf2f(ushort_t b) {
  union { unsigned u; float f; } cvt; cvt.u = ((unsigned)b) << 16; return cvt.f;
}
__device__ __forceinline__ ushort_t f2bf(float f) {
  union { float f; unsigned u; } cvt; cvt.f = f;
  unsigned u = cvt.u;
  u += 0x7fffu + ((u >> 16) & 1u);   // round-to-nearest-even
  return (ushort_t)(u >> 16);
}

#define BM 64
#define BN 64
#define BK 64
#define LDSS (BK + 8)   // 72: pad breaks power-of-2 stride

// Load 16 contiguous values starting at element offset, as bf16 pair.
template <bool F32>
__device__ __forceinline__ void load16(const void* base, size_t elemOff,
                                       short8& lo, short8& hi) {
  if constexpr (F32) {
    const float* p = (const float*)base + elemOff;
    float4v f0 = *(const float4v*)(p);
    float4v f1 = *(const float4v*)(p + 4);
    float4v f2 = *(const float4v*)(p + 8);
    float4v f3 = *(const float4v*)(p + 12);
#pragma unroll
    for (int e = 0; e < 4; ++e) {
      lo[e]     = (short)f2bf(f0[e]);
      lo[e + 4] = (short)f2bf(f1[e]);
      hi[e]     = (short)f2bf(f2[e]);
      hi[e + 4] = (short)f2bf(f3[e]);
    }
  } else {
    const ushort_t* p = (const ushort_t*)base + elemOff;
    lo = *(const short8*)(p);
    hi = *(const short8*)(p + 8);
  }
}

// MODE 0: QKV   (A=x f32, B=Wqkv f32; scatter -> q_ws,k_ws channel-major; v_t token-major)
// MODE 1: S     (A,B bf16 ws; fp32 out, z-batched over bh)
// MODE 2: XCA   (A=v_t,B=attn bf16; bf16 out into xca)
// MODE 3: OUT   (A=xca bf16, B=Wout f32; fp32 out + fp32 bias)
template <int MODE, bool AF32, bool BF32>
__global__ __launch_bounds__(256) void gemm_bt(
    const void* __restrict__ A, int lda, size_t aStrideZ,
    const void* __restrict__ B, int ldb, size_t bStrideZ,
    int K,
    float* __restrict__ outS, size_t cStrideZ,
    float* __restrict__ outF,
    ushort_t* __restrict__ q_ws, ushort_t* __restrict__ k_ws,
    ushort_t* __restrict__ v_t, ushort_t* __restrict__ xca,
    const float* __restrict__ bias) {
  const int z = blockIdx.z;
  const int n0 = blockIdx.x * BN;
  const int m0 = blockIdx.y * BM;

  __shared__ ushort_t sA[BM][LDSS];
  __shared__ ushort_t sB[BN][LDSS];

  const int tid = threadIdx.x;
  const int r = tid >> 2;            // 0..63: row loaded by this thread
  const int cb = (tid & 3) * 16;     // k-column base (16 elems per thread)
  const int w = tid >> 6;            // wave 0..3 -> owns rows [w*16, w*16+16)
  const int lane = tid & 63;
  const int l15 = lane & 15;
  const int quad = lane >> 4;

  float4v acc[4];
#pragma unroll
  for (int t = 0; t < 4; ++t) acc[t] = (float4v){0.f, 0.f, 0.f, 0.f};

  const size_t aRow = (size_t)z * aStrideZ + (size_t)(m0 + r) * lda + cb;
  const size_t bRow = (size_t)z * bStrideZ + (size_t)(n0 + r) * ldb + cb;

  for (int kk = 0; kk < K; kk += BK) {
    short8 a0, a1, b0, b1;
    load16<AF32>(A, aRow + kk, a0, a1);
    load16<BF32>(B, bRow + kk, b0, b1);
    __syncthreads();
    *(short8*)&sA[r][cb] = a0;
    *(short8*)&sA[r][cb + 8] = a1;
    *(short8*)&sB[r][cb] = b0;
    *(short8*)&sB[r][cb + 8] = b1;
    __syncthreads();
#pragma unroll
    for (int k2 = 0; k2 < BK; k2 += 32) {
      short8 af = *(const short8*)&sA[w * 16 + l15][k2 + quad * 8];
#pragma unroll
      for (int t = 0; t < 4; ++t) {
        short8 bf = *(const short8*)&sB[t * 16 + l15][k2 + quad * 8];
        acc[t] = __builtin_amdgcn_mfma_f32_16x16x32_bf16(af, bf, acc[t], 0, 0, 0);
      }
    }
  }

  // Epilogue. C/D layout: col = lane&15 (within 16x16 tile), row = quad*4 + reg.
  if constexpr (MODE == 0) {
#pragma unroll
    for (int t = 0; t < 4; ++t) {
      int gCol = n0 + t * 16 + l15;          // j in [0,1536)
      int t3 = gCol >> 9;                    // 0=q 1=k 2=v (uniform per 64-tile)
      int head = (gCol >> 7) & 3;
      int c = gCol & 127;
      int rowBase = m0 + w * 16 + quad * 4;  // 4-aligned
      int b = rowBase >> 13;
      int n = rowBase & 8191;
      int bh = b * 4 + head;
      if (t3 == 2) {
#pragma unroll
        for (int rg = 0; rg < 4; ++rg)
          v_t[((size_t)bh * 8192 + (n + rg)) * 128 + c] = f2bf(acc[t][rg]);
      } else {
        ushort4v pk;
#pragma unroll
        for (int rg = 0; rg < 4; ++rg) pk[rg] = f2bf(acc[t][rg]);
        ushort_t* dst = (t3 == 0 ? q_ws : k_ws) + ((size_t)bh * 128 + c) * 8192 + n;
        *(ushort4v*)dst = pk;
      }
    }
  } else {
#pragma unroll
    for (int t = 0; t < 4; ++t) {
      int gCol = n0 + t * 16 + l15;
#pragma unroll
      for (int rg = 0; rg < 4; ++rg) {
        int gRow = m0 + w * 16 + quad * 4 + rg;
        float val = acc[t][rg];
        if constexpr (MODE == 1) {
          outS[(size_t)z * cStrideZ + (size_t)gRow * 128 + gCol] = val;
        } else if constexpr (MODE == 2) {
          int b = z >> 2, h = z & 3;
          xca[(((size_t)b * 8192 + gRow) * 512) + h * 128 + gCol] = f2bf(val);
        } else {
          outF[(size_t)gRow * 512 + gCol] = val + bias[gCol];
        }
      }
    }
  }
}

// Per-(tensor,bh,c) L2 norm over N=8192. grid 4096 x block 64.
__global__ void norms_kernel(const ushort_t* __restrict__ q,
                             const ushort_t* __restrict__ k,
                             float* __restrict__ norms) {
  int idx = blockIdx.x;
  const ushort_t* p = ((idx >> 11) ? k : q) + (size_t)(idx & 2047) * 8192;
  int lane = threadIdx.x;
  float s = 0.f;
#pragma unroll
  for (int j = 0; j < 16; ++j) {
    short8 v = *(const short8*)(p + (size_t)(j * 64 + lane) * 8);
#pragma unroll
    for (int e = 0; e < 8; ++e) {
      float f = bf2f((ushort_t)v[e]);
      s += f * f;
    }
  }
#pragma unroll
  for (int off = 32; off; off >>= 1) s += __shfl_xor(s, off);
  if (lane == 0) norms[idx] = sqrtf(s);
}

// Normalize S by row/col norms, temperature, softmax over d. grid (128,16) x 64.
__global__ void attn_softmax(const float* __restrict__ S,
                             const float* __restrict__ norms,
                             const float* __restrict__ temp,
                             ushort_t* __restrict__ attn) {
  int c = blockIdx.x, bh = blockIdx.y, h = bh & 3;
  int lane = threadIdx.x;
  const float* Srow = S + ((size_t)bh * 128 + c) * 128;
  float nq = fmaxf(norms[bh * 128 + c], 1e-12f);
  float T = temp[h];
  float inv_nq_T = T / nq;
  float v0 = Srow[lane] * inv_nq_T / fmaxf(norms[2048 + bh * 128 + lane], 1e-12f);
  float v1 = Srow[lane + 64] * inv_nq_T / fmaxf(norms[2048 + bh * 128 + lane + 64], 1e-12f);
  float m = fmaxf(v0, v1);
#pragma unroll
  for (int off = 32; off; off >>= 1) m = fmaxf(m, __shfl_xor(m, off));
  float e0 = expf(v0 - m), e1 = expf(v1 - m);
  float s = e0 + e1;
#pragma unroll
  for (int off = 32; off; off >>= 1) s += __shfl_xor(s, off);
  float inv = 1.0f / s;
  size_t base = ((size_t)bh * 128 + c) * 128;
  attn[base + lane] = f2bf(e0 * inv);
  attn[base + lane + 64] = f2bf(e1 * inv);
}

extern "C" void kernel_launch(void* const* d_in, const int* in_sizes, int n_in,
                              void* d_out, int out_size, void* d_ws, size_t ws_size,
                              hipStream_t stream) {
  const void*  x    = d_in[0];                 // [4,8192,512] f32
  const void*  Wqkv = d_in[1];                 // [1536,512]   f32
  const void*  Wout = d_in[2];                 // [512,512]    f32
  const float* bout = (const float*)d_in[3];   // [512]        f32
  const float* temp = (const float*)d_in[4];   // [4,1,1]      f32
  float* out = (float*)d_out;                  // [4,8192,512] f32

  char* ws = (char*)d_ws;
  ushort_t* q_ws  = (ushort_t*)(ws);                 // 33,554,432 B
  ushort_t* k_ws  = (ushort_t*)(ws + 33554432);      // 33,554,432 B
  ushort_t* v_t   = (ushort_t*)(ws + 67108864);      // 33,554,432 B
  float*    S     = (float*)(ws + 100663296);        //  1,048,576 B
  float*    norms = (float*)(ws + 101711872);        //     16,384 B
  ushort_t* attn  = (ushort_t*)(ws + 101728256);     //    524,288 B
  ushort_t* xca   = q_ws;                            // reuse (q dead after S)

  dim3 blk(256);

  // 1) QKV: [32768x512] @ [1536x512]^T, scatter epilogue.
  gemm_bt<0, true, true><<<dim3(24, 512, 1), blk, 0, stream>>>(
      x, 512, (size_t)0, Wqkv, 512, (size_t)0, 512,
      nullptr, (size_t)0, nullptr, q_ws, k_ws, v_t, nullptr, nullptr);

  // 2) L2 norms of q,k rows.
  norms_kernel<<<dim3(4096), dim3(64), 0, stream>>>(q_ws, k_ws, norms);

  // 3) S[bh] = q[bh] @ k[bh]^T, K=8192, fp32 out.
  gemm_bt<1, false, false><<<dim3(2, 2, 16), blk, 0, stream>>>(
      q_ws, 8192, (size_t)128 * 8192, k_ws, 8192, (size_t)128 * 8192, 8192,
      S, (size_t)16384, nullptr, nullptr, nullptr, nullptr, nullptr, nullptr);

  // 4) normalize + temperature + softmax -> bf16 attn.
  attn_softmax<<<dim3(128, 16), dim3(64), 0, stream>>>(S, norms, temp, attn);

  // 5) xca[b,n,h*128+c] = sum_d v_t[bh,n,d] * attn[bh,c,d].
  gemm_bt<2, false, false><<<dim3(2, 128, 16), blk, 0, stream>>>(
      v_t, 128, (size_t)8192 * 128, attn, 128, (size_t)16384, 128,
      nullptr, (size_t)0, nullptr, nullptr, nullptr, nullptr, xca, nullptr);

  // 6) out = xca @ Wout^T + b.
  gemm_bt<3, false, true><<<dim3(8, 512, 1), blk, 0, stream>>>(
      xca, 512, (size_t)0, Wout, 512, (size_t)0, 512,
      nullptr, (size_t)0, out, nullptr, nullptr, nullptr, nullptr, bout);
}

// Round 3
// 302.731 us; speedup vs baseline: 1.5828x; 1.5828x over previous
//
#include <hip/hip_runtime.h>

// ChannelAttention (XCA): B=4, N=8192, C=512, heads=4, dh=128. FP32 in/out.
// Pipeline: convert(bf16) -> QKV gemm128 -> norms -> S(split-K) -> softmax(->attn^T)
//           -> W2 = Wout_h @ attn (per bh) -> out = v @ W2^T + bias.
// All GEMMs: C[M][N] = A[M][K] * B[N][K]^T, K contiguous, m97-style 128x128 tile
// with global_load_lds(16B) staging (no LDS pad: wave-uniform base + lane*16).

typedef unsigned short ushort_t;
typedef __attribute__((ext_vector_type(8))) short short8;
typedef __attribute__((ext_vector_type(4))) float float4v;
typedef __attribute__((ext_vector_type(4))) unsigned short ushort4v;

__device__ __forceinline__ float bf2f(ushort_t b) {
  union { unsigned u; float f; } c; c.u = ((unsigned)b) << 16; return c.f;
}
__device__ __forceinline__ ushort_t f2bf(float f) {
  union { float f; unsigned u; } c; c.f = f;
  unsigned u = c.u;
  u += 0x7fffu + ((u >> 16) & 1u);   // RNE
  return (ushort_t)(u >> 16);
}

typedef const __attribute__((address_space(1))) unsigned int guint_t;
typedef __attribute__((address_space(3))) unsigned int luint_t;
__device__ __forceinline__ void gl_lds16(const ushort_t* g, ushort_t* l) {
  __builtin_amdgcn_global_load_lds((guint_t*)g, (luint_t*)l, 16, 0, 0);
}

// fp32 -> bf16 for x (4194304 groups of 4), Wqkv (196608), Wout (65536).
__global__ __launch_bounds__(256) void convert_bf16(
    const float* __restrict__ x, const float* __restrict__ w1,
    const float* __restrict__ w2, ushort_t* __restrict__ xb,
    ushort_t* __restrict__ w1b, ushort_t* __restrict__ w2b) {
  int g = blockIdx.x * 256 + threadIdx.x;
  const float* src; ushort_t* dst; int off;
  if (g < 4194304)      { src = x;  dst = xb;  off = g; }
  else if (g < 4390912) { src = w1; dst = w1b; off = g - 4194304; }
  else                  { src = w2; dst = w2b; off = g - 4390912; }
  size_t e = (size_t)off * 4;
  float4v f = *(const float4v*)(src + e);
  ushort4v o;
#pragma unroll
  for (int i = 0; i < 4; ++i) o[i] = f2bf(f[i]);
  *(ushort4v*)(dst + e) = o;
}

// MODE 0: QKV  A=x_bf[32768x512] B=Wqkv_bf[1536x512]; scatter q,k chan-major, v token-major
// MODE 1: S    per (bh, splitK s): q[bh],k[bh] chunk; fp32 partial out
// MODE 2: W2   A=Wout_bf(+h*128)[512x(512)] B=attn_t[bh][128x128]; bf16 W2b out
// MODE 3: OUT  A=v_tok[b][8192x512] B=W2b[b][512x512]; fp32 out + bias
template <int MODE>
__global__ __launch_bounds__(256) void gemm128(
    const ushort_t* __restrict__ A, const ushort_t* __restrict__ B,
    float* __restrict__ outF, ushort_t* __restrict__ outU,
    ushort_t* __restrict__ q_ws, ushort_t* __restrict__ k_ws,
    ushort_t* __restrict__ v_tok, const float* __restrict__ bias) {
  const int tid = threadIdx.x;
  const int z = blockIdx.z;
  const int n0 = blockIdx.x * 128;
  const int m0 = blockIdx.y * 128;

  int lda, ldb, K;
  const ushort_t *Ab, *Bb;
  if constexpr (MODE == 0) { lda = 512; ldb = 512; K = 512; Ab = A; Bb = B; }
  else if constexpr (MODE == 1) {
    int bh = z >> 3, s = z & 7;
    lda = 8192; ldb = 8192; K = 1024;
    Ab = A + (size_t)bh * 1048576 + s * 1024;
    Bb = B + (size_t)bh * 1048576 + s * 1024;
  } else if constexpr (MODE == 2) {
    lda = 512; ldb = 128; K = 128;
    Ab = A + (z & 3) * 128;
    Bb = B + (size_t)z * 16384;
  } else {
    lda = 512; ldb = 512; K = 512;
    Ab = A + (size_t)z * 8192 * 512;
    Bb = B + (size_t)z * 512 * 512;
  }

  __shared__ ushort_t sA[128 * 64];
  __shared__ ushort_t sB[128 * 64];

  const int lr = tid >> 3;          // 0..31
  const int lc = (tid & 7) * 8;     // element col within 64
  const ushort_t* ga = Ab + (size_t)(m0 + lr) * lda + lc;
  const ushort_t* gb = Bb + (size_t)(n0 + lr) * ldb + lc;
  ushort_t* la = &sA[lr * 64 + lc];
  ushort_t* lb = &sB[lr * 64 + lc];
  const size_t aStep = (size_t)32 * lda;
  const size_t bStep = (size_t)32 * ldb;

  const int w = tid >> 6;
  const int lane = tid & 63;
  const int l15 = lane & 15;
  const int quad = lane >> 4;
  const int wm = (w >> 1) * 64, wn = (w & 1) * 64;

  float4v acc[4][4];
#pragma unroll
  for (int i = 0; i < 4; ++i)
#pragma unroll
    for (int j = 0; j < 4; ++j) acc[i][j] = (float4v){0.f, 0.f, 0.f, 0.f};

  for (int kk = 0; kk < K; kk += 64) {
    __syncthreads();   // previous compute done before overwrite
#pragma unroll
    for (int i = 0; i < 4; ++i) {
      gl_lds16(ga + i * aStep + kk, la + i * 2048);
      gl_lds16(gb + i * bStep + kk, lb + i * 2048);
    }
    __syncthreads();   // drains vmcnt: staging visible
#pragma unroll
    for (int k2 = 0; k2 < 64; k2 += 32) {
      short8 af[4], bfr[4];
#pragma unroll
      for (int i = 0; i < 4; ++i)
        af[i] = *(const short8*)&sA[(wm + i * 16 + l15) * 64 + k2 + quad * 8];
#pragma unroll
      for (int j = 0; j < 4; ++j)
        bfr[j] = *(const short8*)&sB[(wn + j * 16 + l15) * 64 + k2 + quad * 8];
#pragma unroll
      for (int i = 0; i < 4; ++i)
#pragma unroll
        for (int j = 0; j < 4; ++j)
          acc[i][j] = __builtin_amdgcn_mfma_f32_16x16x32_bf16(af[i], bfr[j], acc[i][j], 0, 0, 0);
    }
  }

  // C/D layout: col = lane&15, row = quad*4 + reg (verified by round-2 pass).
  if constexpr (MODE == 0) {
    const int t3 = n0 >> 9;              // 0=q 1=k 2=v (128-col block = one head)
    const int h = (n0 >> 7) & 3;
    if (t3 == 2) {
#pragma unroll
      for (int i = 0; i < 4; ++i)
#pragma unroll
        for (int j = 0; j < 4; ++j) {
          int col = wn + j * 16 + l15;
#pragma unroll
          for (int rg = 0; rg < 4; ++rg) {
            int gr = m0 + wm + i * 16 + quad * 4 + rg;
            int b = gr >> 13, n = gr & 8191;
            v_tok[((size_t)b * 8192 + n) * 512 + h * 128 + col] = f2bf(acc[i][j][rg]);
          }
        }
    } else {
      ushort_t* dstT = t3 ? k_ws : q_ws;
#pragma unroll
      for (int i = 0; i < 4; ++i) {
        int gr = m0 + wm + i * 16 + quad * 4;
        int b = gr >> 13, n = gr & 8191;
        int bh = b * 4 + h;
#pragma unroll
        for (int j = 0; j < 4; ++j) {
          ushort4v pk;
#pragma unroll
          for (int rg = 0; rg < 4; ++rg) pk[rg] = f2bf(acc[i][j][rg]);
          *(ushort4v*)(dstT + ((size_t)bh * 128 + (wn + j * 16 + l15)) * 8192 + n) = pk;
        }
      }
    }
  } else if constexpr (MODE == 1) {
#pragma unroll
    for (int i = 0; i < 4; ++i)
#pragma unroll
      for (int j = 0; j < 4; ++j)
#pragma unroll
        for (int rg = 0; rg < 4; ++rg)
          outF[(size_t)z * 16384 + (size_t)(wm + i * 16 + quad * 4 + rg) * 128 +
               wn + j * 16 + l15] = acc[i][j][rg];
  } else if constexpr (MODE == 2) {
    int b = z >> 2, h = z & 3;
#pragma unroll
    for (int i = 0; i < 4; ++i)
#pragma unroll
      for (int j = 0; j < 4; ++j)
#pragma unroll
        for (int rg = 0; rg < 4; ++rg)
          outU[((size_t)b * 512 + m0 + wm + i * 16 + quad * 4 + rg) * 512 +
               h * 128 + wn + j * 16 + l15] = f2bf(acc[i][j][rg]);
  } else {
#pragma unroll
    for (int i = 0; i < 4; ++i)
#pragma unroll
      for (int j = 0; j < 4; ++j) {
        int gcol = n0 + wn + j * 16 + l15;
        float bv = bias[gcol];
#pragma unroll
        for (int rg = 0; rg < 4; ++rg)
          outF[((size_t)z * 8192 + m0 + wm + i * 16 + quad * 4 + rg) * 512 + gcol] =
              acc[i][j][rg] + bv;
      }
  }
}

// L2 norms over N=8192 per (tensor,bh,c). 4 waves/block, wave per channel.
__global__ __launch_bounds__(256) void norms_kernel(
    const ushort_t* __restrict__ q, const ushort_t* __restrict__ k,
    float* __restrict__ norms) {
  int w = threadIdx.x >> 6, lane = threadIdx.x & 63;
  int idx = blockIdx.x * 4 + w;
  const ushort_t* p = ((idx >> 11) ? k : q) + (size_t)(idx & 2047) * 8192;
  float s = 0.f;
#pragma unroll
  for (int it = 0; it < 16; ++it) {
    short8 v = *(const short8*)(p + (size_t)(it * 64 + lane) * 8);
#pragma unroll
    for (int e = 0; e < 8; ++e) {
      float f = bf2f((ushort_t)v[e]);
      s += f * f;
    }
  }
#pragma unroll
  for (int off = 32; off; off >>= 1) s += __shfl_xor(s, off);
  if (lane == 0) norms[idx] = sqrtf(s);
}

// Sum split-K partials, normalize by norms, temperature, softmax over d,
// write attn TRANSPOSED: attn_t[bh][d][c]. grid (128,16) x 64.
__global__ void attn_softmax(const float* __restrict__ Sp,
                             const float* __restrict__ norms,
                             const float* __restrict__ temp,
                             ushort_t* __restrict__ attn_t) {
  int c = blockIdx.x, bh = blockIdx.y, h = bh & 3;
  int lane = threadIdx.x;
  const float* base = Sp + (size_t)bh * 8 * 16384 + (size_t)c * 128;
  float v0 = 0.f, v1 = 0.f;
#pragma unroll
  for (int s = 0; s < 8; ++s) {
    v0 += base[s * 16384 + lane];
    v1 += base[s * 16384 + lane + 64];
  }
  float nq = fmaxf(norms[bh * 128 + c], 1e-12f);
  float sc = temp[h] / nq;
  v0 = v0 * sc / fmaxf(norms[2048 + bh * 128 + lane], 1e-12f);
  v1 = v1 * sc / fmaxf(norms[2048 + bh * 128 + lane + 64], 1e-12f);
  float m = fmaxf(v0, v1);
#pragma unroll
  for (int off = 32; off; off >>= 1) m = fmaxf(m, __shfl_xor(m, off));
  float e0 = expf(v0 - m), e1 = expf(v1 - m);
  float s = e0 + e1;
#pragma unroll
  for (int off = 32; off; off >>= 1) s += __shfl_xor(s, off);
  float inv = 1.0f / s;
  attn_t[(size_t)bh * 16384 + (size_t)lane * 128 + c] = f2bf(e0 * inv);
  attn_t[(size_t)bh * 16384 + (size_t)(lane + 64) * 128 + c] = f2bf(e1 * inv);
}

extern "C" void kernel_launch(void* const* d_in, const int* in_sizes, int n_in,
                              void* d_out, int out_size, void* d_ws, size_t ws_size,
                              hipStream_t stream) {
  const float* x    = (const float*)d_in[0];   // [4,8192,512]
  const float* Wqkv = (const float*)d_in[1];   // [1536,512]
  const float* Wout = (const float*)d_in[2];   // [512,512]
  const float* bout = (const float*)d_in[3];   // [512]
  const float* temp = (const float*)d_in[4];   // [4,1,1]
  float* out = (float*)d_out;                  // [4,8192,512] f32

  char* ws = (char*)d_ws;
  // Region 0 (33.5 MB): x_bf during QKV; then reused by S_par/norms/attn_t/W2b.
  ushort_t* x_bf  = (ushort_t*)(ws);
  float*    S_par = (float*)(ws);                    // 8,388,608 B (after QKV)
  float*    norms = (float*)(ws + 8388608);          //    16,384 B
  ushort_t* attnT = (ushort_t*)(ws + 8404992);       //   524,288 B
  ushort_t* W2b   = (ushort_t*)(ws + 8929280);       // 2,097,152 B
  ushort_t* q_ws  = (ushort_t*)(ws + 33554432);      // 33,554,432 B chan-major [bh][c][n]
  ushort_t* k_ws  = (ushort_t*)(ws + 67108864);      // 33,554,432 B
  ushort_t* v_tok = (ushort_t*)(ws + 100663296);     // 33,554,432 B token-major [b][n][h*128+d]
  ushort_t* Wqkvb = (ushort_t*)(ws + 134217728);     // 1,572,864 B
  ushort_t* Woutb = (ushort_t*)(ws + 135790592);     //   524,288 B (end 136,314,880)

  // 1) fp32 -> bf16 conversions.
  convert_bf16<<<dim3(17408), dim3(256), 0, stream>>>(x, Wqkv, Wout, x_bf, Wqkvb, Woutb);

  // 2) QKV GEMM + scatter.
  gemm128<0><<<dim3(12, 256, 1), dim3(256), 0, stream>>>(
      x_bf, Wqkvb, nullptr, nullptr, q_ws, k_ws, v_tok, nullptr);

  // 3) L2 norms of q,k channels.
  norms_kernel<<<dim3(1024), dim3(256), 0, stream>>>(q_ws, k_ws, norms);

  // 4) S partials: split-K=8 over N=8192.
  gemm128<1><<<dim3(1, 1, 128), dim3(256), 0, stream>>>(
      q_ws, k_ws, S_par, nullptr, nullptr, nullptr, nullptr, nullptr);

  // 5) reduce + normalize + softmax -> attn^T (bf16).
  attn_softmax<<<dim3(128, 16), dim3(64), 0, stream>>>(S_par, norms, temp, attnT);

  // 6) W2[bh][o][d] = sum_c Wout[o,h*128+c] * attn[bh][c][d].
  gemm128<2><<<dim3(1, 4, 16), dim3(256), 0, stream>>>(
      Woutb, attnT, nullptr, W2b, nullptr, nullptr, nullptr, nullptr);

  // 7) out[b] = v_tok[b] @ W2b[b]^T + bias.
  gemm128<3><<<dim3(4, 64, 4), dim3(256), 0, stream>>>(
      v_tok, W2b, out, nullptr, nullptr, nullptr, nullptr, bout);
}